// Round 1
// baseline (474.366 us; speedup 1.0000x reference)
//
#include <hip/hip_runtime.h>
#include <hip/hip_bf16.h>
#include <math.h>

// Shapes: B=16, H=512, L=2048, N=64
#define HH 512
#define NN 64
#define LLEN 2048
#define BB 16

typedef __attribute__((ext_vector_type(8))) short short8;
typedef __attribute__((ext_vector_type(4))) float f32x4;

__device__ inline unsigned short f2bf(float f) {
    union { float f; unsigned int u; } v; v.f = f;
    unsigned int x = v.u;
    unsigned int r = (x + 0x7fffu + ((x >> 16) & 1u)) >> 16;
    return (unsigned short)r;
}

// ---------------- K_A: per-(h,n) coefficients: lambda = exp(dt_Lambda), c = Wk * exp(-P_max)
__global__ __launch_bounds__(256) void k_coeffs(
    const float* __restrict__ log_dt,   // (H,2)
    const float* __restrict__ Lambda,   // (N,2)
    const float* __restrict__ W,        // (1,H,N,2)
    float* __restrict__ lam_re, float* __restrict__ lam_im,
    float* __restrict__ c_re,  float* __restrict__ c_im) {
    int idx = blockIdx.x * 256 + threadIdx.x;      // 0..H*N-1
    int h = idx >> 6, n = idx & 63;
    float lre = Lambda[n * 2 + 0], lim = Lambda[n * 2 + 1];
    float dtr = expf(log_dt[h * 2 + 0]);
    float dti = expf(log_dt[h * 2 + 1]);
    float ar = dtr * lre;      // dt_Lambda real
    float ai = dti * lim;      // dt_Lambda imag
    float pos = (lre > 0.0f) ? 1.0f : 0.0f;
    // lambda = exp(ar + i*ai)
    float e = expf(ar);
    float lamr = e * cosf(ai), lami = e * sinf(ai);
    // exp(-P_max), P_max = dt_Lambda * (pos*(L-1))
    float pm = pos * (float)(LLEN - 1);
    float er = expf(-ar * pm);
    float epr = er * cosf(-ai * pm), epi = er * sinf(-ai * pm);
    // dt_Lambda_neg = dt_Lambda * (1-2pos)
    float sgn = 1.0f - 2.0f * pos;
    float nr = ar * sgn, ni = ai * sgn;
    // num = exp(nr+i ni) - 1
    float en = expf(nr);
    float numr = en * cosf(ni) - 1.0f, numi = en * sinf(ni);
    // den = exp((nr+i ni)*L) - 1
    float eL = expf(nr * (float)LLEN);
    float denr = eL * cosf(ni * (float)LLEN) - 1.0f;
    float deni = eL * sinf(ni * (float)LLEN);
    // x = den * Lam
    float xr = denr * lre - deni * lim;
    float xi = denr * lim + deni * lre;
    // recip = conj(x) / (|x|^2 + eps)
    float d = xr * xr + xi * xi + 1e-7f;
    float rr = xr / d, ri = -xi / d;
    // Wk = Wc * num * recip
    float wr = W[(h * 64 + n) * 2 + 0], wi = W[(h * 64 + n) * 2 + 1];
    float t1r = wr * numr - wi * numi;
    float t1i = wr * numi + wi * numr;
    float wkr = t1r * rr - t1i * ri;
    float wki = t1r * ri + t1i * rr;
    // c = Wk * exp(-P_max)
    float cr = wkr * epr - wki * epi;
    float ci = wkr * epi + wki * epr;
    lam_re[idx] = lamr; lam_im[idx] = lami;
    c_re[idx] = cr;     c_im[idx] = ci;
}

// ---------------- K_W: out_weight fp32 -> bf16
__global__ __launch_bounds__(256) void k_w2b(const float* __restrict__ w,
                                             unsigned short* __restrict__ wb) {
    int idx = blockIdx.x * 256 + threadIdx.x;   // 0..262143
    wb[idx] = f2bf(w[idx]);
}

// ---------------- K_B: recurrence scan. 16 lanes per (b,h); 4 modes per lane.
// Writes G[b,h,l] = bf16(gelu(conv + D*u))
__global__ __launch_bounds__(256) void k_scan(
    const float* __restrict__ u,        // (B,H,L)
    const float* __restrict__ D,        // (1,H)
    const float* __restrict__ lam_re, const float* __restrict__ lam_im,
    const float* __restrict__ c_re,  const float* __restrict__ c_im,
    unsigned short* __restrict__ G) {
    __shared__ float u_s[16 * 68];               // 16 groups x 64 (+4 pad)
    int tid = threadIdx.x;
    int g = tid >> 4;          // group within block: 0..15
    int sub = tid & 15;        // lane within group
    int bh = blockIdx.x * 16 + g;                // 0..8191
    int h = bh & (HH - 1);
    float lr[4], li[4], cr[4], ci[4], sr[4], si[4];
#pragma unroll
    for (int j = 0; j < 4; ++j) {
        int idx = h * 64 + (sub + 16 * j);
        lr[j] = lam_re[idx]; li[j] = lam_im[idx];
        cr[j] = c_re[idx];   ci[j] = c_im[idx];
        sr[j] = 0.0f; si[j] = 0.0f;
    }
    float Dh = D[h];
    const float* up = u + (size_t)bh * LLEN;
    unsigned short* Gp = G + (size_t)bh * LLEN;

    for (int l0 = 0; l0 < LLEN; l0 += 64) {
        __syncthreads();
        // stage this group's 64 u values: each of 16 lanes loads float4
        {
            const float4* src = (const float4*)(up + l0);
            float4 v = src[sub];
            *(float4*)&u_s[g * 68 + sub * 4] = v;
        }
        __syncthreads();
#pragma unroll
        for (int q = 0; q < 4; ++q) {
            float ykeep = 0.0f;
#pragma unroll
            for (int t = 0; t < 16; ++t) {
                int lc = q * 16 + t;
                float uv = u_s[g * 68 + lc];
                float acc0 = 0.0f, acc1 = 0.0f;
#pragma unroll
                for (int j = 0; j < 4; ++j) {
                    float so = sr[j];
                    float t0 = fmaf(lr[j], so, uv);
                    sr[j] = fmaf(-li[j], si[j], t0);
                    si[j] = fmaf(lr[j], si[j], li[j] * so);
                    acc0 = fmaf(cr[j], sr[j], acc0);
                    acc1 = fmaf(ci[j], si[j], acc1);
                }
                float acc = acc0 - acc1;
                acc += __shfl_xor(acc, 1);
                acc += __shfl_xor(acc, 2);
                acc += __shfl_xor(acc, 4);
                acc += __shfl_xor(acc, 8);
                float y = fmaf(Dh, uv, acc);
                ykeep = (t == sub) ? y : ykeep;
            }
            // exact-erf GELU on the value this lane kept, store bf16
            float yg = 0.5f * ykeep * (1.0f + erff(ykeep * 0.70710678118654752f));
            Gp[l0 + q * 16 + sub] = f2bf(yg);
        }
    }
}

// ---------------- K_D: out[b,v,l] = sum_u W[v,u]*G[b,u,l] + bias[v], bf16 MFMA
__global__ __launch_bounds__(256) void k_proj(
    const unsigned short* __restrict__ G,    // (B,H,L) bf16
    const unsigned short* __restrict__ Wb,   // (H,H) bf16
    const float* __restrict__ bias,          // (H,1)
    float* __restrict__ out) {               // (B,H,L)
    __shared__ unsigned short Bl[64 * 40];   // [l(64)][u(32)] pitch 40
    int tid = threadIdx.x;
    int wid = tid >> 6, lane = tid & 63;
    int wm = wid & 1, wn = wid >> 1;
    int quad = lane >> 4, sub = lane & 15;
    int v0 = blockIdx.x * 64;
    int l0 = blockIdx.y * 64;
    int b = blockIdx.z;

    f32x4 acc[2][2];
#pragma unroll
    for (int i = 0; i < 2; ++i)
#pragma unroll
        for (int j = 0; j < 2; ++j)
            acc[i][j] = (f32x4){0.f, 0.f, 0.f, 0.f};

    int urow = tid & 31;            // staged u-row within k-block
    int lb = (tid >> 5) * 8;        // l-base (8 l's per thread)

    for (int k0 = 0; k0 < HH; k0 += 32) {
        __syncthreads();
        // stage B tile: G[b, k0+urow, l0+lb .. +8) -> Bl[l][u]
        short8 gv = *(const short8*)(G + (((size_t)b * HH + (k0 + urow)) * LLEN) + l0 + lb);
#pragma unroll
        for (int i = 0; i < 8; ++i) {
            Bl[(lb + i) * 40 + urow] = ((unsigned short)gv[i]);
        }
        __syncthreads();
        // A fragments from global (W is L1/L2 resident)
        short8 a0 = *(const short8*)(Wb + (size_t)(v0 + wm * 32 + 0  + sub) * HH + k0 + quad * 8);
        short8 a1 = *(const short8*)(Wb + (size_t)(v0 + wm * 32 + 16 + sub) * HH + k0 + quad * 8);
        // B fragments from LDS (transposed layout: [l][u], k-contiguous)
        short8 b0 = *(const short8*)(&Bl[(wn * 32 + 0  + sub) * 40 + quad * 8]);
        short8 b1 = *(const short8*)(&Bl[(wn * 32 + 16 + sub) * 40 + quad * 8]);
        acc[0][0] = __builtin_amdgcn_mfma_f32_16x16x32_bf16(a0, b0, acc[0][0], 0, 0, 0);
        acc[0][1] = __builtin_amdgcn_mfma_f32_16x16x32_bf16(a0, b1, acc[0][1], 0, 0, 0);
        acc[1][0] = __builtin_amdgcn_mfma_f32_16x16x32_bf16(a1, b0, acc[1][0], 0, 0, 0);
        acc[1][1] = __builtin_amdgcn_mfma_f32_16x16x32_bf16(a1, b1, acc[1][1], 0, 0, 0);
    }
    // epilogue: D[row=quad*4+r][col=sub]
#pragma unroll
    for (int ms = 0; ms < 2; ++ms) {
#pragma unroll
        for (int ns = 0; ns < 2; ++ns) {
#pragma unroll
            for (int r = 0; r < 4; ++r) {
                int v = v0 + wm * 32 + ms * 16 + quad * 4 + r;
                int l = l0 + wn * 32 + ns * 16 + sub;
                out[((size_t)b * HH + v) * LLEN + l] = acc[ms][ns][r] + bias[v];
            }
        }
    }
}

extern "C" void kernel_launch(void* const* d_in, const int* in_sizes, int n_in,
                              void* d_out, int out_size, void* d_ws, size_t ws_size,
                              hipStream_t stream) {
    const float* u       = (const float*)d_in[0];
    const float* log_dt  = (const float*)d_in[1];
    const float* Lambda  = (const float*)d_in[2];
    const float* W       = (const float*)d_in[3];
    const float* D       = (const float*)d_in[4];
    const float* out_w   = (const float*)d_in[5];
    const float* out_b   = (const float*)d_in[6];
    float* out = (float*)d_out;

    char* ws = (char*)d_ws;
    float* lam_re = (float*)(ws + 0);
    float* lam_im = (float*)(ws + 131072);
    float* c_re   = (float*)(ws + 262144);
    float* c_im   = (float*)(ws + 393216);
    unsigned short* Wb = (unsigned short*)(ws + 524288);   // 512KB
    unsigned short* G  = (unsigned short*)(ws + 1048576);  // ~33.5MB

    hipLaunchKernelGGL(k_coeffs, dim3(128), dim3(256), 0, stream,
                       log_dt, Lambda, W, lam_re, lam_im, c_re, c_im);
    hipLaunchKernelGGL(k_w2b, dim3(1024), dim3(256), 0, stream, out_w, Wb);
    hipLaunchKernelGGL(k_scan, dim3(512), dim3(256), 0, stream,
                       u, D, lam_re, lam_im, c_re, c_im, G);
    hipLaunchKernelGGL(k_proj, dim3(8, 32, 16), dim3(256), 0, stream,
                       G, Wb, out_b, out);
}

// Round 2
// 323.964 us; speedup vs baseline: 1.4643x; 1.4643x over previous
//
#include <hip/hip_runtime.h>
#include <hip/hip_bf16.h>
#include <math.h>

// Shapes: B=16, H=512, L=2048, N=64
#define HH 512
#define NN 64
#define LLEN 2048
#define BB 16

typedef __attribute__((ext_vector_type(8))) short short8;
typedef __attribute__((ext_vector_type(4))) float f32x4;

// XOR swizzle on element index within a row (bits 3..4) to break LDS bank collisions
#define SW(j,e) ((e) ^ (((j)&3)<<3))

__device__ inline unsigned short f2bf(float f) {
    union { float f; unsigned int u; } v; v.f = f;
    unsigned int x = v.u;
    unsigned int r = (x + 0x7fffu + ((x >> 16) & 1u)) >> 16;
    return (unsigned short)r;
}
__device__ inline float bf2f(unsigned short x) {
    union { unsigned int u; float f; } v; v.u = ((unsigned int)x) << 16;
    return v.f;
}

// ---------------- K_A: per-(h,n) coefficients: lambda = exp(dt_Lambda), c = Wk * exp(-P_max)
__global__ __launch_bounds__(256) void k_coeffs(
    const float* __restrict__ log_dt,   // (H,2)
    const float* __restrict__ Lambda,   // (N,2)
    const float* __restrict__ W,        // (1,H,N,2)
    float* __restrict__ c_re,  float* __restrict__ c_im) {
    int idx = blockIdx.x * 256 + threadIdx.x;      // 0..H*N-1
    int h = idx >> 6, n = idx & 63;
    float lre = Lambda[n * 2 + 0], lim = Lambda[n * 2 + 1];
    float dtr = expf(log_dt[h * 2 + 0]);
    float dti = expf(log_dt[h * 2 + 1]);
    float ar = dtr * lre;      // dt_Lambda real
    float ai = dti * lim;      // dt_Lambda imag
    float pos = (lre > 0.0f) ? 1.0f : 0.0f;
    // exp(-P_max), P_max = dt_Lambda * (pos*(L-1))   (pos==0 in practice: skew evals - 0.5)
    float pm = pos * (float)(LLEN - 1);
    float er = expf(-ar * pm);
    float epr = er * cosf(-ai * pm), epi = er * sinf(-ai * pm);
    // dt_Lambda_neg = dt_Lambda * (1-2pos)
    float sgn = 1.0f - 2.0f * pos;
    float nr = ar * sgn, ni = ai * sgn;
    // num = exp(nr+i ni) - 1
    float en = expf(nr);
    float numr = en * cosf(ni) - 1.0f, numi = en * sinf(ni);
    // den = exp((nr+i ni)*L) - 1
    float eL = expf(nr * (float)LLEN);
    float denr = eL * cosf(ni * (float)LLEN) - 1.0f;
    float deni = eL * sinf(ni * (float)LLEN);
    // x = den * Lam
    float xr = denr * lre - deni * lim;
    float xi = denr * lim + deni * lre;
    // recip = conj(x) / (|x|^2 + eps)
    float d = xr * xr + xi * xi + 1e-7f;
    float rr = xr / d, ri = -xi / d;
    // Wk = Wc * num * recip
    float wr = W[(h * 64 + n) * 2 + 0], wi = W[(h * 64 + n) * 2 + 1];
    float t1r = wr * numr - wi * numi;
    float t1i = wr * numi + wi * numr;
    float wkr = t1r * rr - t1i * ri;
    float wki = t1r * ri + t1i * rr;
    // c = Wk * exp(-P_max)
    c_re[idx] = wkr * epr - wki * epi;
    c_im[idx] = wkr * epi + wki * epr;
}

// ---------------- K_W: out_weight fp32 -> bf16
__global__ __launch_bounds__(256) void k_w2b(const float* __restrict__ w,
                                             unsigned short* __restrict__ wb) {
    int idx = blockIdx.x * 256 + threadIdx.x;   // 0..262143
    wb[idx] = f2bf(w[idx]);
}

// ---------------- K_PREP: per-h matrices for the chunked scan.
// Tm[i][i'] = k[i-i'] (lower tri) + D_h on diag, k[d] = Re sum_n c_n lam_n^d
// Are/Aim[n][i] = lam_n^(63-i);  Pre[i][n] = Re(c_n lam_n^(i+1)); Pim[i][n] = -Im(c_n lam_n^(i+1))
// lam64[n] = lam_n^64 (fp32 complex)
__global__ __launch_bounds__(64) void k_prep(
    const float* __restrict__ log_dt, const float* __restrict__ Lambda,
    const float* __restrict__ c_re, const float* __restrict__ c_im,
    const float* __restrict__ D,
    unsigned short* __restrict__ Tm,
    unsigned short* __restrict__ Are, unsigned short* __restrict__ Aim,
    unsigned short* __restrict__ Pre, unsigned short* __restrict__ Pim,
    float2* __restrict__ lam64) {
    int h = blockIdx.x;
    int ln = threadIdx.x;                       // 0..63
    __shared__ float ar_s[64], ai_s[64], cr_s[64], ci_s[64];
    __shared__ unsigned short T_s[64 * 64];
    float dtr = expf(log_dt[h * 2 + 0]);
    float dti = expf(log_dt[h * 2 + 1]);
    float ar = dtr * Lambda[ln * 2 + 0];
    float ai = dti * Lambda[ln * 2 + 1];
    float cr = c_re[h * 64 + ln], ci = c_im[h * 64 + ln];
    ar_s[ln] = ar; ai_s[ln] = ai; cr_s[ln] = cr; ci_s[ln] = ci;
    float e64 = expf(64.f * ar);
    lam64[h * 64 + ln] = make_float2(e64 * cosf(64.f * ai), e64 * sinf(64.f * ai));
    // zero T_s (each thread a column, all rows -> every element exactly once)
    for (int r = 0; r < 64; ++r) T_s[r * 64 + ln] = 0;
    __syncthreads();
    size_t base = (size_t)h * 4096;
    // Are/Aim: lane = column i, loop over modes n
    {
        float fi = (float)(63 - ln);
        for (int n = 0; n < 64; ++n) {
            float w = expf(fi * ar_s[n]);
            Are[base + n * 64 + ln] = f2bf(w * cosf(fi * ai_s[n]));
            Aim[base + n * 64 + ln] = f2bf(w * sinf(fi * ai_s[n]));
        }
    }
    // Pre/Pim: lane = mode n, incremental p = c*lam^(i+1)
    {
        float e1 = expf(ar);
        float lr = e1 * cosf(ai), li = e1 * sinf(ai);
        float pr = cr * lr - ci * li, pi = cr * li + ci * lr;
        for (int i = 0; i < 64; ++i) {
            Pre[base + i * 64 + ln] = f2bf(pr);
            Pim[base + i * 64 + ln] = f2bf(-pi);   // negated for MFMA accumulate
            float nr2 = pr * lr - pi * li;
            pi = pr * li + pi * lr;
            pr = nr2;
        }
    }
    // T: lane = d computes k[d], fills diagonal band d
    {
        float fd = (float)ln;
        float acc = 0.f;
        for (int n = 0; n < 64; ++n) {
            float w = expf(fd * ar_s[n]);
            acc += cr_s[n] * (w * cosf(fd * ai_s[n])) - ci_s[n] * (w * sinf(fd * ai_s[n]));
        }
        if (ln == 0) acc += D[h];                 // fold skip connection into diagonal
        unsigned short kb = f2bf(acc);
        for (int i = ln; i < 64; ++i) T_s[i * 64 + (i - ln)] = kb;
    }
    __syncthreads();
    // coalesced copy T_s -> global
    {
        const short8* src = (const short8*)T_s;
        short8* dst = (short8*)(Tm + base);
        for (int t = 0; t < 8; ++t) dst[t * 64 + ln] = src[t * 64 + ln];
    }
}

// ---------------- K_SCAN2: chunked MFMA scan. 1 wave per (b,h).
__global__ __launch_bounds__(64) void k_scan2(
    const float* __restrict__ u,
    const unsigned short* __restrict__ Tm,
    const unsigned short* __restrict__ Are, const unsigned short* __restrict__ Aim,
    const unsigned short* __restrict__ Pre, const unsigned short* __restrict__ Pim,
    const float2* __restrict__ lam64,
    unsigned short* __restrict__ G) {
    __shared__ unsigned short Ub[32 * 72];    // [j][i] bf16, pitch 72, swizzled
    __shared__ unsigned short Sre[32 * 72];   // V then (in-place) S, real
    __shared__ unsigned short Sim_[32 * 72];  // V then S, imag
    int ln = threadIdx.x;
    int sub = ln & 15, quad = ln >> 4;
    int bh = blockIdx.x;                      // h*16 + b : h-major for L2 reuse of matrices
    int h = bh >> 4, b = bh & 15;
    const float* up = u + ((size_t)b * HH + h) * LLEN;
    unsigned short* Gp = G + ((size_t)b * HH + h) * LLEN;
    size_t mb = (size_t)h * 4096;

    // ---- stage u -> Ub bf16
    for (int t = 0; t < 8; ++t) {
        int l = t * 256 + ln * 4;
        float4 v = *(const float4*)(up + l);
        int j = l >> 6, i = l & 63;
        unsigned int p0 = (unsigned int)f2bf(v.x) | ((unsigned int)f2bf(v.y) << 16);
        unsigned int p1 = (unsigned int)f2bf(v.z) | ((unsigned int)f2bf(v.w) << 16);
        *(uint2*)&Ub[j * 72 + SW(j, i)] = make_uint2(p0, p1);
    }
    __syncthreads();

    // ---- matmul1: V[n][j] = sum_i lam_n^(63-i) * U[i][j]
    f32x4 vr[4][2], vi[4][2];
#pragma unroll
    for (int mt = 0; mt < 4; ++mt)
#pragma unroll
        for (int nt = 0; nt < 2; ++nt) {
            vr[mt][nt] = (f32x4){0.f, 0.f, 0.f, 0.f};
            vi[mt][nt] = (f32x4){0.f, 0.f, 0.f, 0.f};
        }
#pragma unroll
    for (int kc = 0; kc < 2; ++kc) {
        short8 bu0 = *(const short8*)&Ub[sub * 72 + SW(sub, kc * 32 + quad * 8)];
        short8 bu1 = *(const short8*)&Ub[(16 + sub) * 72 + SW(16 + sub, kc * 32 + quad * 8)];
#pragma unroll
        for (int mt = 0; mt < 4; ++mt) {
            size_t ab = mb + (size_t)(mt * 16 + sub) * 64 + kc * 32 + quad * 8;
            short8 ar8 = *(const short8*)(Are + ab);
            short8 ai8 = *(const short8*)(Aim + ab);
            vr[mt][0] = __builtin_amdgcn_mfma_f32_16x16x32_bf16(ar8, bu0, vr[mt][0], 0, 0, 0);
            vr[mt][1] = __builtin_amdgcn_mfma_f32_16x16x32_bf16(ar8, bu1, vr[mt][1], 0, 0, 0);
            vi[mt][0] = __builtin_amdgcn_mfma_f32_16x16x32_bf16(ai8, bu0, vi[mt][0], 0, 0, 0);
            vi[mt][1] = __builtin_amdgcn_mfma_f32_16x16x32_bf16(ai8, bu1, vi[mt][1], 0, 0, 0);
        }
    }
    // write V -> LDS [j][n] (C layout: n = mt*16+quad*4+r, j = nt*16+sub)
#pragma unroll
    for (int mt = 0; mt < 4; ++mt)
#pragma unroll
        for (int nt = 0; nt < 2; ++nt) {
            int jj = nt * 16 + sub;
            int e0 = mt * 16 + quad * 4;
            uint2 pr, pi;
            pr.x = (unsigned int)f2bf(vr[mt][nt][0]) | ((unsigned int)f2bf(vr[mt][nt][1]) << 16);
            pr.y = (unsigned int)f2bf(vr[mt][nt][2]) | ((unsigned int)f2bf(vr[mt][nt][3]) << 16);
            pi.x = (unsigned int)f2bf(vi[mt][nt][0]) | ((unsigned int)f2bf(vi[mt][nt][1]) << 16);
            pi.y = (unsigned int)f2bf(vi[mt][nt][2]) | ((unsigned int)f2bf(vi[mt][nt][3]) << 16);
            *(uint2*)&Sre[jj * 72 + SW(jj, e0)] = pr;
            *(uint2*)&Sim_[jj * 72 + SW(jj, e0)] = pi;
        }
    __syncthreads();

    // ---- scan over 32 chunks: lane = mode. S[j] = state before chunk j (in-place over V)
    {
        float2 l64 = lam64[(size_t)h * 64 + ln];
        float sr = 0.f, si = 0.f;
        for (int j = 0; j < 32; ++j) {
            int a = j * 72 + SW(j, ln);
            float vrr = bf2f(Sre[a]);
            float vii = bf2f(Sim_[a]);
            Sre[a] = f2bf(sr);
            Sim_[a] = f2bf(si);
            float nr = fmaf(l64.x, sr, fmaf(-l64.y, si, vrr));
            float ni = fmaf(l64.y, sr, fmaf(l64.x, si, vii));
            sr = nr; si = ni;
        }
    }
    __syncthreads();

    // ---- matmul2+3: Y[i][j] = T@U + Pre@Sre + (-Pim)@Sim
    f32x4 y[4][2];
#pragma unroll
    for (int mt = 0; mt < 4; ++mt)
#pragma unroll
        for (int nt = 0; nt < 2; ++nt) y[mt][nt] = (f32x4){0.f, 0.f, 0.f, 0.f};
#pragma unroll
    for (int kc = 0; kc < 2; ++kc) {
        int eo = kc * 32 + quad * 8;
        short8 bsr0 = *(const short8*)&Sre[sub * 72 + SW(sub, eo)];
        short8 bsr1 = *(const short8*)&Sre[(16 + sub) * 72 + SW(16 + sub, eo)];
        short8 bsi0 = *(const short8*)&Sim_[sub * 72 + SW(sub, eo)];
        short8 bsi1 = *(const short8*)&Sim_[(16 + sub) * 72 + SW(16 + sub, eo)];
        short8 bu0  = *(const short8*)&Ub[sub * 72 + SW(sub, eo)];
        short8 bu1  = *(const short8*)&Ub[(16 + sub) * 72 + SW(16 + sub, eo)];
#pragma unroll
        for (int mt = 0; mt < 4; ++mt) {
            size_t ab = mb + (size_t)(mt * 16 + sub) * 64 + eo;
            short8 at8 = *(const short8*)(Tm + ab);
            short8 pr8 = *(const short8*)(Pre + ab);
            short8 pi8 = *(const short8*)(Pim + ab);
            y[mt][0] = __builtin_amdgcn_mfma_f32_16x16x32_bf16(at8, bu0, y[mt][0], 0, 0, 0);
            y[mt][1] = __builtin_amdgcn_mfma_f32_16x16x32_bf16(at8, bu1, y[mt][1], 0, 0, 0);
            y[mt][0] = __builtin_amdgcn_mfma_f32_16x16x32_bf16(pr8, bsr0, y[mt][0], 0, 0, 0);
            y[mt][1] = __builtin_amdgcn_mfma_f32_16x16x32_bf16(pr8, bsr1, y[mt][1], 0, 0, 0);
            y[mt][0] = __builtin_amdgcn_mfma_f32_16x16x32_bf16(pi8, bsi0, y[mt][0], 0, 0, 0);
            y[mt][1] = __builtin_amdgcn_mfma_f32_16x16x32_bf16(pi8, bsi1, y[mt][1], 0, 0, 0);
        }
    }
    __syncthreads();

    // ---- GELU (exact erf) + stage to Ub (reuse)
#pragma unroll
    for (int mt = 0; mt < 4; ++mt)
#pragma unroll
        for (int nt = 0; nt < 2; ++nt) {
            int jj = nt * 16 + sub;
            int e0 = mt * 16 + quad * 4;
            float g[4];
#pragma unroll
            for (int r = 0; r < 4; ++r) {
                float yv = y[mt][nt][r];
                g[r] = 0.5f * yv * (1.0f + erff(yv * 0.70710678118654752f));
            }
            uint2 p;
            p.x = (unsigned int)f2bf(g[0]) | ((unsigned int)f2bf(g[1]) << 16);
            p.y = (unsigned int)f2bf(g[2]) | ((unsigned int)f2bf(g[3]) << 16);
            *(uint2*)&Ub[jj * 72 + SW(jj, e0)] = p;
        }
    __syncthreads();

    // ---- coalesced store of G (bf16)
    for (int t = 0; t < 4; ++t) {
        int l = t * 512 + ln * 8;
        int j = l >> 6, i = l & 63;
        uint4 q = *(const uint4*)&Ub[j * 72 + SW(j, i)];
        *(uint4*)(Gp + l) = q;
    }
}

// ---------------- K_D: out[b,v,l] = sum_u W[v,u]*G[b,u,l] + bias[v], bf16 MFMA
__global__ __launch_bounds__(256) void k_proj(
    const unsigned short* __restrict__ G,    // (B,H,L) bf16
    const unsigned short* __restrict__ Wb,   // (H,H) bf16
    const float* __restrict__ bias,          // (H,1)
    float* __restrict__ out) {               // (B,H,L)
    __shared__ unsigned short Bl[64 * 40];   // [l(64)][u(32)] pitch 40
    int tid = threadIdx.x;
    int wid = tid >> 6, lane = tid & 63;
    int wm = wid & 1, wn = wid >> 1;
    int quad = lane >> 4, sub = lane & 15;
    int v0 = blockIdx.x * 64;
    int l0 = blockIdx.y * 64;
    int b = blockIdx.z;

    f32x4 acc[2][2];
#pragma unroll
    for (int i = 0; i < 2; ++i)
#pragma unroll
        for (int j = 0; j < 2; ++j)
            acc[i][j] = (f32x4){0.f, 0.f, 0.f, 0.f};

    int urow = tid & 31;
    int lb = (tid >> 5) * 8;

    for (int k0 = 0; k0 < HH; k0 += 32) {
        __syncthreads();
        short8 gv = *(const short8*)(G + (((size_t)b * HH + (k0 + urow)) * LLEN) + l0 + lb);
#pragma unroll
        for (int i = 0; i < 8; ++i) {
            Bl[(lb + i) * 40 + urow] = ((unsigned short)gv[i]);
        }
        __syncthreads();
        short8 a0 = *(const short8*)(Wb + (size_t)(v0 + wm * 32 + 0  + sub) * HH + k0 + quad * 8);
        short8 a1 = *(const short8*)(Wb + (size_t)(v0 + wm * 32 + 16 + sub) * HH + k0 + quad * 8);
        short8 b0 = *(const short8*)(&Bl[(wn * 32 + 0  + sub) * 40 + quad * 8]);
        short8 b1 = *(const short8*)(&Bl[(wn * 32 + 16 + sub) * 40 + quad * 8]);
        acc[0][0] = __builtin_amdgcn_mfma_f32_16x16x32_bf16(a0, b0, acc[0][0], 0, 0, 0);
        acc[0][1] = __builtin_amdgcn_mfma_f32_16x16x32_bf16(a0, b1, acc[0][1], 0, 0, 0);
        acc[1][0] = __builtin_amdgcn_mfma_f32_16x16x32_bf16(a1, b0, acc[1][0], 0, 0, 0);
        acc[1][1] = __builtin_amdgcn_mfma_f32_16x16x32_bf16(a1, b1, acc[1][1], 0, 0, 0);
    }
#pragma unroll
    for (int ms = 0; ms < 2; ++ms) {
#pragma unroll
        for (int ns = 0; ns < 2; ++ns) {
#pragma unroll
            for (int r = 0; r < 4; ++r) {
                int v = v0 + wm * 32 + ms * 16 + quad * 4 + r;
                int l = l0 + wn * 32 + ns * 16 + sub;
                out[((size_t)b * HH + v) * LLEN + l] = acc[ms][ns][r] + bias[v];
            }
        }
    }
}

extern "C" void kernel_launch(void* const* d_in, const int* in_sizes, int n_in,
                              void* d_out, int out_size, void* d_ws, size_t ws_size,
                              hipStream_t stream) {
    const float* u       = (const float*)d_in[0];
    const float* log_dt  = (const float*)d_in[1];
    const float* Lambda  = (const float*)d_in[2];
    const float* W       = (const float*)d_in[3];
    const float* D       = (const float*)d_in[4];
    const float* out_w   = (const float*)d_in[5];
    const float* out_b   = (const float*)d_in[6];
    float* out = (float*)d_out;

    char* ws = (char*)d_ws;
    float* c_re   = (float*)(ws + 0);
    float* c_im   = (float*)(ws + 131072);
    unsigned short* Wb = (unsigned short*)(ws + 524288);   // 512KB..1MB
    unsigned short* G  = (unsigned short*)(ws + 1048576);  // 32 MiB
    size_t off = 1048576 + (size_t)BB * HH * LLEN * 2;     // 34,603,008
    const size_t MSZ = (size_t)HH * 4096 * 2;              // 4 MiB per matrix
    unsigned short* TmB  = (unsigned short*)(ws + off); off += MSZ;
    unsigned short* AreB = (unsigned short*)(ws + off); off += MSZ;
    unsigned short* AimB = (unsigned short*)(ws + off); off += MSZ;
    unsigned short* PreB = (unsigned short*)(ws + off); off += MSZ;
    unsigned short* PimB = (unsigned short*)(ws + off); off += MSZ;
    float2* lam64B = (float2*)(ws + off);                  // 256 KB

    hipLaunchKernelGGL(k_coeffs, dim3(128), dim3(256), 0, stream,
                       log_dt, Lambda, W, c_re, c_im);
    hipLaunchKernelGGL(k_w2b, dim3(1024), dim3(256), 0, stream, out_w, Wb);
    hipLaunchKernelGGL(k_prep, dim3(512), dim3(64), 0, stream,
                       log_dt, Lambda, c_re, c_im, D,
                       TmB, AreB, AimB, PreB, PimB, lam64B);
    hipLaunchKernelGGL(k_scan2, dim3(8192), dim3(64), 0, stream,
                       u, TmB, AreB, AimB, PreB, PimB, lam64B, G);
    hipLaunchKernelGGL(k_proj, dim3(8, 32, 16), dim3(256), 0, stream,
                       G, Wb, out_b, out);
}

// Round 3
// 255.437 us; speedup vs baseline: 1.8571x; 1.2683x over previous
//
#include <hip/hip_runtime.h>
#include <hip/hip_bf16.h>
#include <math.h>

// Shapes: B=16, H=512, L=2048, N=64
#define HH 512
#define NN 64
#define LLEN 2048
#define BB 16

typedef __attribute__((ext_vector_type(8))) short short8;
typedef __attribute__((ext_vector_type(4))) float f32x4;

// XOR swizzle on element index within a row (bits 3..4) to break LDS bank collisions
#define SW(j,e) ((e) ^ (((j)&3)<<3))

__device__ inline unsigned short f2bf(float f) {
    union { float f; unsigned int u; } v; v.f = f;
    unsigned int x = v.u;
    unsigned int r = (x + 0x7fffu + ((x >> 16) & 1u)) >> 16;
    return (unsigned short)r;
}
__device__ inline float bf2f(unsigned short x) {
    union { unsigned int u; float f; } v; v.u = ((unsigned int)x) << 16;
    return v.f;
}

__device__ inline void gload_lds16(const unsigned short* g, unsigned short* l) {
    __builtin_amdgcn_global_load_lds(
        (const __attribute__((address_space(1))) void*)g,
        (__attribute__((address_space(3))) void*)l, 16, 0, 0);
}

// ---------------- K_A: per-(h,n) coefficients
__global__ __launch_bounds__(256) void k_coeffs(
    const float* __restrict__ log_dt,   // (H,2)
    const float* __restrict__ Lambda,   // (N,2)
    const float* __restrict__ W,        // (1,H,N,2)
    float* __restrict__ c_re,  float* __restrict__ c_im) {
    int idx = blockIdx.x * 256 + threadIdx.x;      // 0..H*N-1
    int h = idx >> 6, n = idx & 63;
    float lre = Lambda[n * 2 + 0], lim = Lambda[n * 2 + 1];
    float dtr = expf(log_dt[h * 2 + 0]);
    float dti = expf(log_dt[h * 2 + 1]);
    float ar = dtr * lre;
    float ai = dti * lim;
    float pos = (lre > 0.0f) ? 1.0f : 0.0f;
    float pm = pos * (float)(LLEN - 1);
    float er = expf(-ar * pm);
    float epr = er * cosf(-ai * pm), epi = er * sinf(-ai * pm);
    float sgn = 1.0f - 2.0f * pos;
    float nr = ar * sgn, ni = ai * sgn;
    float en = expf(nr);
    float numr = en * cosf(ni) - 1.0f, numi = en * sinf(ni);
    float eL = expf(nr * (float)LLEN);
    float denr = eL * cosf(ni * (float)LLEN) - 1.0f;
    float deni = eL * sinf(ni * (float)LLEN);
    float xr = denr * lre - deni * lim;
    float xi = denr * lim + deni * lre;
    float d = xr * xr + xi * xi + 1e-7f;
    float rr = xr / d, ri = -xi / d;
    float wr = W[(h * 64 + n) * 2 + 0], wi = W[(h * 64 + n) * 2 + 1];
    float t1r = wr * numr - wi * numi;
    float t1i = wr * numi + wi * numr;
    float wkr = t1r * rr - t1i * ri;
    float wki = t1r * ri + t1i * rr;
    c_re[idx] = wkr * epr - wki * epi;
    c_im[idx] = wkr * epi + wki * epr;
}

// ---------------- K_W: out_weight fp32 -> bf16
__global__ __launch_bounds__(256) void k_w2b(const float* __restrict__ w,
                                             unsigned short* __restrict__ wb) {
    int idx = blockIdx.x * 256 + threadIdx.x;
    wb[idx] = f2bf(w[idx]);
}

// ---------------- K_PREP (rewritten, 256 thr, closed-form, 1 block per h)
__global__ __launch_bounds__(256) void k_prep(
    const float* __restrict__ log_dt, const float* __restrict__ Lambda,
    const float* __restrict__ c_re, const float* __restrict__ c_im,
    const float* __restrict__ D,
    unsigned short* __restrict__ Tm,
    unsigned short* __restrict__ Are, unsigned short* __restrict__ Aim,
    unsigned short* __restrict__ Pre, unsigned short* __restrict__ Pim,
    float2* __restrict__ lam64) {
    int h = blockIdx.x;
    int tid = threadIdx.x;
    __shared__ float ar_s[64], ai_s[64], cr_s[64], ci_s[64], k_s[64];
    if (tid < 64) {
        int n = tid;
        float dtr = expf(log_dt[h * 2 + 0]);
        float dti = expf(log_dt[h * 2 + 1]);
        float ar = dtr * Lambda[n * 2 + 0];
        float ai = dti * Lambda[n * 2 + 1];
        ar_s[n] = ar; ai_s[n] = ai;
        cr_s[n] = c_re[h * 64 + n]; ci_s[n] = c_im[h * 64 + n];
        float e64 = expf(64.f * ar);
        lam64[h * 64 + n] = make_float2(e64 * cosf(64.f * ai), e64 * sinf(64.f * ai));
    }
    __syncthreads();
    size_t base = (size_t)h * 4096;
#pragma unroll 4
    for (int e = 0; e < 16; ++e) {
        int idx = e * 256 + tid;       // 0..4095
        int r = idx >> 6, q = idx & 63;
        // Are/Aim: [n=r][i=q] = lam_r^(63-q)
        {
            float fi = (float)(63 - q);
            float w = expf(fi * ar_s[r]);
            Are[base + idx] = f2bf(w * cosf(fi * ai_s[r]));
            Aim[base + idx] = f2bf(w * sinf(fi * ai_s[r]));
        }
        // Pre/Pim: [i=r][n=q] = c_q * lam_q^(r+1)  (Pim negated)
        {
            float t = (float)(r + 1);
            float w = expf(t * ar_s[q]);
            float pr = w * cosf(t * ai_s[q]), pii = w * sinf(t * ai_s[q]);
            Pre[base + idx] = f2bf(cr_s[q] * pr - ci_s[q] * pii);
            Pim[base + idx] = f2bf(-(cr_s[q] * pii + ci_s[q] * pr));
        }
    }
    if (tid < 64) {
        float fd = (float)tid, acc = 0.f;
        for (int n = 0; n < 64; ++n) {
            float w = expf(fd * ar_s[n]);
            acc += cr_s[n] * (w * cosf(fd * ai_s[n])) - ci_s[n] * (w * sinf(fd * ai_s[n]));
        }
        if (tid == 0) acc += D[h];
        k_s[tid] = acc;
    }
    __syncthreads();
#pragma unroll 4
    for (int e = 0; e < 16; ++e) {
        int idx = e * 256 + tid;
        int i = idx >> 6, ip = idx & 63;
        Tm[base + idx] = (ip <= i) ? f2bf(k_s[i - ip]) : (unsigned short)0;
    }
}

// ---------------- K_SCAN2: chunked MFMA scan. 1 wave per (b,h). (unchanged)
__global__ __launch_bounds__(64) void k_scan2(
    const float* __restrict__ u,
    const unsigned short* __restrict__ Tm,
    const unsigned short* __restrict__ Are, const unsigned short* __restrict__ Aim,
    const unsigned short* __restrict__ Pre, const unsigned short* __restrict__ Pim,
    const float2* __restrict__ lam64,
    unsigned short* __restrict__ G) {
    __shared__ unsigned short Ub[32 * 72];
    __shared__ unsigned short Sre[32 * 72];
    __shared__ unsigned short Sim_[32 * 72];
    int ln = threadIdx.x;
    int sub = ln & 15, quad = ln >> 4;
    int bh = blockIdx.x;
    int h = bh >> 4, b = bh & 15;
    const float* up = u + ((size_t)b * HH + h) * LLEN;
    unsigned short* Gp = G + ((size_t)b * HH + h) * LLEN;
    size_t mb = (size_t)h * 4096;

    for (int t = 0; t < 8; ++t) {
        int l = t * 256 + ln * 4;
        float4 v = *(const float4*)(up + l);
        int j = l >> 6, i = l & 63;
        unsigned int p0 = (unsigned int)f2bf(v.x) | ((unsigned int)f2bf(v.y) << 16);
        unsigned int p1 = (unsigned int)f2bf(v.z) | ((unsigned int)f2bf(v.w) << 16);
        *(uint2*)&Ub[j * 72 + SW(j, i)] = make_uint2(p0, p1);
    }
    __syncthreads();

    f32x4 vr[4][2], vi[4][2];
#pragma unroll
    for (int mt = 0; mt < 4; ++mt)
#pragma unroll
        for (int nt = 0; nt < 2; ++nt) {
            vr[mt][nt] = (f32x4){0.f, 0.f, 0.f, 0.f};
            vi[mt][nt] = (f32x4){0.f, 0.f, 0.f, 0.f};
        }
#pragma unroll
    for (int kc = 0; kc < 2; ++kc) {
        short8 bu0 = *(const short8*)&Ub[sub * 72 + SW(sub, kc * 32 + quad * 8)];
        short8 bu1 = *(const short8*)&Ub[(16 + sub) * 72 + SW(16 + sub, kc * 32 + quad * 8)];
#pragma unroll
        for (int mt = 0; mt < 4; ++mt) {
            size_t ab = mb + (size_t)(mt * 16 + sub) * 64 + kc * 32 + quad * 8;
            short8 ar8 = *(const short8*)(Are + ab);
            short8 ai8 = *(const short8*)(Aim + ab);
            vr[mt][0] = __builtin_amdgcn_mfma_f32_16x16x32_bf16(ar8, bu0, vr[mt][0], 0, 0, 0);
            vr[mt][1] = __builtin_amdgcn_mfma_f32_16x16x32_bf16(ar8, bu1, vr[mt][1], 0, 0, 0);
            vi[mt][0] = __builtin_amdgcn_mfma_f32_16x16x32_bf16(ai8, bu0, vi[mt][0], 0, 0, 0);
            vi[mt][1] = __builtin_amdgcn_mfma_f32_16x16x32_bf16(ai8, bu1, vi[mt][1], 0, 0, 0);
        }
    }
#pragma unroll
    for (int mt = 0; mt < 4; ++mt)
#pragma unroll
        for (int nt = 0; nt < 2; ++nt) {
            int jj = nt * 16 + sub;
            int e0 = mt * 16 + quad * 4;
            uint2 pr, pi;
            pr.x = (unsigned int)f2bf(vr[mt][nt][0]) | ((unsigned int)f2bf(vr[mt][nt][1]) << 16);
            pr.y = (unsigned int)f2bf(vr[mt][nt][2]) | ((unsigned int)f2bf(vr[mt][nt][3]) << 16);
            pi.x = (unsigned int)f2bf(vi[mt][nt][0]) | ((unsigned int)f2bf(vi[mt][nt][1]) << 16);
            pi.y = (unsigned int)f2bf(vi[mt][nt][2]) | ((unsigned int)f2bf(vi[mt][nt][3]) << 16);
            *(uint2*)&Sre[jj * 72 + SW(jj, e0)] = pr;
            *(uint2*)&Sim_[jj * 72 + SW(jj, e0)] = pi;
        }
    __syncthreads();

    {
        float2 l64 = lam64[(size_t)h * 64 + ln];
        float sr = 0.f, si = 0.f;
        for (int j = 0; j < 32; ++j) {
            int a = j * 72 + SW(j, ln);
            float vrr = bf2f(Sre[a]);
            float vii = bf2f(Sim_[a]);
            Sre[a] = f2bf(sr);
            Sim_[a] = f2bf(si);
            float nr = fmaf(l64.x, sr, fmaf(-l64.y, si, vrr));
            float ni = fmaf(l64.y, sr, fmaf(l64.x, si, vii));
            sr = nr; si = ni;
        }
    }
    __syncthreads();

    f32x4 y[4][2];
#pragma unroll
    for (int mt = 0; mt < 4; ++mt)
#pragma unroll
        for (int nt = 0; nt < 2; ++nt) y[mt][nt] = (f32x4){0.f, 0.f, 0.f, 0.f};
#pragma unroll
    for (int kc = 0; kc < 2; ++kc) {
        int eo = kc * 32 + quad * 8;
        short8 bsr0 = *(const short8*)&Sre[sub * 72 + SW(sub, eo)];
        short8 bsr1 = *(const short8*)&Sre[(16 + sub) * 72 + SW(16 + sub, eo)];
        short8 bsi0 = *(const short8*)&Sim_[sub * 72 + SW(sub, eo)];
        short8 bsi1 = *(const short8*)&Sim_[(16 + sub) * 72 + SW(16 + sub, eo)];
        short8 bu0  = *(const short8*)&Ub[sub * 72 + SW(sub, eo)];
        short8 bu1  = *(const short8*)&Ub[(16 + sub) * 72 + SW(16 + sub, eo)];
#pragma unroll
        for (int mt = 0; mt < 4; ++mt) {
            size_t ab = mb + (size_t)(mt * 16 + sub) * 64 + eo;
            short8 at8 = *(const short8*)(Tm + ab);
            short8 pr8 = *(const short8*)(Pre + ab);
            short8 pi8 = *(const short8*)(Pim + ab);
            y[mt][0] = __builtin_amdgcn_mfma_f32_16x16x32_bf16(at8, bu0, y[mt][0], 0, 0, 0);
            y[mt][1] = __builtin_amdgcn_mfma_f32_16x16x32_bf16(at8, bu1, y[mt][1], 0, 0, 0);
            y[mt][0] = __builtin_amdgcn_mfma_f32_16x16x32_bf16(pr8, bsr0, y[mt][0], 0, 0, 0);
            y[mt][1] = __builtin_amdgcn_mfma_f32_16x16x32_bf16(pr8, bsr1, y[mt][1], 0, 0, 0);
            y[mt][0] = __builtin_amdgcn_mfma_f32_16x16x32_bf16(pi8, bsi0, y[mt][0], 0, 0, 0);
            y[mt][1] = __builtin_amdgcn_mfma_f32_16x16x32_bf16(pi8, bsi1, y[mt][1], 0, 0, 0);
        }
    }
    __syncthreads();

#pragma unroll
    for (int mt = 0; mt < 4; ++mt)
#pragma unroll
        for (int nt = 0; nt < 2; ++nt) {
            int jj = nt * 16 + sub;
            int e0 = mt * 16 + quad * 4;
            float g[4];
#pragma unroll
            for (int r = 0; r < 4; ++r) {
                float yv = y[mt][nt][r];
                g[r] = 0.5f * yv * (1.0f + erff(yv * 0.70710678118654752f));
            }
            uint2 p;
            p.x = (unsigned int)f2bf(g[0]) | ((unsigned int)f2bf(g[1]) << 16);
            p.y = (unsigned int)f2bf(g[2]) | ((unsigned int)f2bf(g[3]) << 16);
            *(uint2*)&Ub[jj * 72 + SW(jj, e0)] = p;
        }
    __syncthreads();

    for (int t = 0; t < 4; ++t) {
        int l = t * 512 + ln * 8;
        int j = l >> 6, i = l & 63;
        uint4 q = *(const uint4*)&Ub[j * 72 + SW(j, i)];
        *(uint4*)(Gp + l) = q;
    }
}

// ---------------- K_TR: G[b][u][l] -> Gt[b][l][u], 64x64 LDS tiles
__global__ __launch_bounds__(256) void k_tr(const unsigned short* __restrict__ G,
                                            unsigned short* __restrict__ Gt) {
    __shared__ unsigned short T[64 * 72];
    int tid = threadIdx.x;
    int l0 = blockIdx.x * 64, u0 = blockIdx.y * 64, b = blockIdx.z;
    {
        int ur = tid >> 2, ls = (tid & 3) * 16;
        const unsigned short* src = G + ((size_t)(b * HH + u0 + ur)) * LLEN + l0 + ls;
        *(uint4*)&T[ur * 72 + ls]     = *(const uint4*)(src);
        *(uint4*)&T[ur * 72 + ls + 8] = *(const uint4*)(src + 8);
    }
    __syncthreads();
    {
        int lr = tid >> 2, us = (tid & 3) * 16;
        unsigned short tmp[16];
#pragma unroll
        for (int k2 = 0; k2 < 16; ++k2) tmp[k2] = T[(us + k2) * 72 + lr];
        unsigned short* dst = Gt + ((size_t)(b * LLEN + l0 + lr)) * HH + u0 + us;
        *(uint4*)(dst)     = *(uint4*)&tmp[0];
        *(uint4*)(dst + 8) = *(uint4*)&tmp[8];
    }
}

// ---------------- K_PROJ: out[b,v,l] = sum_u W[v,u]*Gt[b,l,u] + bias[v]
// m97-style: 128x128 tile, BK=64, global_load_lds staging, XOR chunk swizzle.
__global__ __launch_bounds__(256) void k_proj(
    const unsigned short* __restrict__ Gt,   // (B,L,H) bf16
    const unsigned short* __restrict__ Wb,   // (H,H) bf16
    const float* __restrict__ bias,          // (H,1)
    float* __restrict__ out) {               // (B,H,L)
    __shared__ unsigned short As[128 * 64];
    __shared__ unsigned short Bs[128 * 64];
    int tid = threadIdx.x;
    int w = tid >> 6, ln = tid & 63;
    int wm = w & 1, wn = w >> 1;
    int quad = ln >> 4, sub = ln & 15;
    int v0 = blockIdx.x * 128, l0 = blockIdx.y * 128, b = blockIdx.z;
    int r_in = ln >> 3, cch = ln & 7;
    int gch = cch ^ r_in;     // XOR source swizzle (row&7 == r_in)

    f32x4 acc[4][4];
#pragma unroll
    for (int mt = 0; mt < 4; ++mt)
#pragma unroll
        for (int nt = 0; nt < 4; ++nt) acc[mt][nt] = (f32x4){0.f, 0.f, 0.f, 0.f};

    for (int k0 = 0; k0 < HH; k0 += 64) {
        __syncthreads();
#pragma unroll
        for (int i = 0; i < 4; ++i) {
            int row = w * 32 + i * 8 + r_in;
            const unsigned short* ga = Wb + (size_t)(v0 + row) * HH + k0 + gch * 8;
            gload_lds16(ga, &As[(w * 32 + i * 8) * 64]);
            const unsigned short* gb = Gt + ((size_t)(b * LLEN + l0 + row)) * HH + k0 + gch * 8;
            gload_lds16(gb, &Bs[(w * 32 + i * 8) * 64]);
        }
        __syncthreads();
#pragma unroll
        for (int kc = 0; kc < 2; ++kc) {
            int ch = (kc * 4 + quad) ^ (sub & 7);
            short8 af[4], bf[4];
#pragma unroll
            for (int mt = 0; mt < 4; ++mt)
                af[mt] = *(const short8*)&As[(wm * 64 + mt * 16 + sub) * 64 + ch * 8];
#pragma unroll
            for (int nt = 0; nt < 4; ++nt)
                bf[nt] = *(const short8*)&Bs[(wn * 64 + nt * 16 + sub) * 64 + ch * 8];
#pragma unroll
            for (int mt = 0; mt < 4; ++mt)
#pragma unroll
                for (int nt = 0; nt < 4; ++nt)
                    acc[mt][nt] = __builtin_amdgcn_mfma_f32_16x16x32_bf16(af[mt], bf[nt], acc[mt][nt], 0, 0, 0);
        }
    }
    // epilogue: D[row=quad*4+i][col=sub]
#pragma unroll
    for (int mt = 0; mt < 4; ++mt) {
#pragma unroll
        for (int i = 0; i < 4; ++i) {
            int v = v0 + wm * 64 + mt * 16 + quad * 4 + i;
            float bv = bias[v];
#pragma unroll
            for (int nt = 0; nt < 4; ++nt) {
                int l = l0 + wn * 64 + nt * 16 + sub;
                out[((size_t)b * HH + v) * LLEN + l] = acc[mt][nt][i] + bv;
            }
        }
    }
}

extern "C" void kernel_launch(void* const* d_in, const int* in_sizes, int n_in,
                              void* d_out, int out_size, void* d_ws, size_t ws_size,
                              hipStream_t stream) {
    const float* u       = (const float*)d_in[0];
    const float* log_dt  = (const float*)d_in[1];
    const float* Lambda  = (const float*)d_in[2];
    const float* W       = (const float*)d_in[3];
    const float* D       = (const float*)d_in[4];
    const float* out_w   = (const float*)d_in[5];
    const float* out_b   = (const float*)d_in[6];
    float* out = (float*)d_out;

    char* ws = (char*)d_ws;
    float* c_re   = (float*)(ws + 0);
    float* c_im   = (float*)(ws + 131072);
    unsigned short* Wb = (unsigned short*)(ws + 524288);   // 512KB..1MB
    unsigned short* G  = (unsigned short*)(ws + 1048576);  // 32 MiB -> ends 34,603,008
    size_t moff = 34603008;
    const size_t MSZ = (size_t)HH * 4096 * 2;              // 4 MiB per matrix
    unsigned short* TmB  = (unsigned short*)(ws + moff);
    unsigned short* AreB = (unsigned short*)(ws + moff + 1 * MSZ);
    unsigned short* AimB = (unsigned short*)(ws + moff + 2 * MSZ);
    unsigned short* PreB = (unsigned short*)(ws + moff + 3 * MSZ);
    unsigned short* PimB = (unsigned short*)(ws + moff + 4 * MSZ);
    float2* lam64B = (float2*)(ws + moff + 5 * MSZ);
    // Gt overlaps the (dead after k_scan2) matrix region
    unsigned short* Gt = (unsigned short*)(ws + moff);     // 32 MiB -> ends ~66.6MB

    hipLaunchKernelGGL(k_coeffs, dim3(128), dim3(256), 0, stream,
                       log_dt, Lambda, W, c_re, c_im);
    hipLaunchKernelGGL(k_w2b, dim3(1024), dim3(256), 0, stream, out_w, Wb);
    hipLaunchKernelGGL(k_prep, dim3(512), dim3(256), 0, stream,
                       log_dt, Lambda, c_re, c_im, D,
                       TmB, AreB, AimB, PreB, PimB, lam64B);
    hipLaunchKernelGGL(k_scan2, dim3(8192), dim3(64), 0, stream,
                       u, TmB, AreB, AimB, PreB, PimB, lam64B, G);
    hipLaunchKernelGGL(k_tr, dim3(32, 8, 16), dim3(256), 0, stream, G, Gt);
    hipLaunchKernelGGL(k_proj, dim3(4, 16, 16), dim3(256), 0, stream,
                       Gt, Wb, out_b, out);
}